// Round 8
// baseline (4532.706 us; speedup 1.0000x reference)
//
#include <hip/hip_runtime.h>
#include <stdint.h>

// ---------------------------------------------------------------------------
// StageNet forward on MI355X — ROUND 8.
// ROOT CAUSE FOUND (R6 override experiment): output buffer is FLOAT32, not
// bf16 — rounds 3-7 wrote bf16 u16 into a fp32 buffer (checker decodes
// word i ~ out[2i+1] -> absmax 0.0798, override of u16[0] invisible). All
// float inputs are fp32 too (reference uses jnp.float32; detector confirmed:
// it selected the fp32 path in rounds 3-7 and produced near-correct values).
// Fix: final store as float. Pipeline otherwise = round 5:
//   detect dtype -> canonicalize (embed/Wk->bf16 for MFMA, Wr/smalls->fp32,
//   Wc->bf16 [o][k][h]) -> PH1 MFMA gather-GEMM XKb(bf16) -> monolithic
//   k_scan (1 block/batch, 50 steps in LDS fp32, theme/conv/Wo fused).
// ---------------------------------------------------------------------------

typedef unsigned short u16;
typedef short bf16x8 __attribute__((ext_vector_type(8)));
typedef float f32x4 __attribute__((ext_vector_type(4)));

__device__ __forceinline__ float bf2f(u16 u) {
  union { unsigned int i; float f; } v;
  v.i = ((unsigned int)u) << 16;
  return v.f;
}
__device__ __forceinline__ u16 f2bf(float f) {
  union { float f; unsigned int i; } v;
  v.f = f;
  unsigned int r = (v.i + 0x7fffu + ((v.i >> 16) & 1u)) >> 16;
  return (u16)r;
}
__device__ __forceinline__ float ldf(const void* p, size_t i, int isbf) {
  return isbf ? bf2f(((const u16*)p)[i]) : ((const float*)p)[i];
}
__device__ __forceinline__ float sigf(float x) { return 1.f / (1.f + __expf(-x)); }
__device__ __forceinline__ float tanhf_(float x) {
  float cx = fminf(fmaxf(x, -15.f), 15.f);
  float e = __expf(2.f * cx);
  return (e - 1.f) / (e + 1.f);
}
__device__ __forceinline__ float dot8_bf(const u16* w, const float* lp) {
  uint4 wv = *(const uint4*)w;
  union { unsigned int u; float f; } a0, a1;
  float s;
  a0.u = wv.x << 16; a1.u = wv.x & 0xffff0000u;
  s = lp[0] * a0.f + lp[1] * a1.f;
  a0.u = wv.y << 16; a1.u = wv.y & 0xffff0000u;
  s += lp[2] * a0.f + lp[3] * a1.f;
  a0.u = wv.z << 16; a1.u = wv.z & 0xffff0000u;
  s += lp[4] * a0.f + lp[5] * a1.f;
  a0.u = wv.w << 16; a1.u = wv.w & 0xffff0000u;
  s += lp[6] * a0.f + lp[7] * a1.f;
  return s;
}

// ------------------------- dtype detection (kept as safety) ----------------
// fp32 packing: words 64..127 = embed row-0 dims 64..127 = exact zeros ->
// flag=0. bf16 packing: those words hold row-1 values -> flag=1.
__global__ void k_detect(const unsigned int* __restrict__ emb_raw,
                         int* __restrict__ flag) {
  if (blockIdx.x == 0 && threadIdx.x == 0) {
    int cnt = 0;
    for (int i = 64; i < 128; ++i) {
      unsigned int u = emb_raw[i];
      unsigned int lo = u & 0xffffu;
      unsigned int ex = (lo >> 7) & 0xffu;
      if (lo != 0 && ex >= 100 && ex <= 126) ++cnt;
    }
    *flag = (cnt >= 32) ? 1 : 0;
  }
}

// ------------------------- canonicalization --------------------------------
__global__ void k_cvt_emb(const void* __restrict__ src, u16* __restrict__ dst,
                          const int* __restrict__ flagp) {
  int isbf = *flagp;
  int n = 10001 * 128;
  int i = blockIdx.x * blockDim.x + threadIdx.x;
  int stride = gridDim.x * blockDim.x;
  for (; i < n; i += stride)
    dst[i] = isbf ? ((const u16*)src)[i] : f2bf(((const float*)src)[i]);
}

__global__ void k_repack_wk(const void* __restrict__ wk, u16* __restrict__ wkp,
                            const int* __restrict__ flagp) {
  int isbf = *flagp;
  size_t i = (size_t)blockIdx.x * blockDim.x + threadIdx.x;
  size_t total = (size_t)1664 * 8192;
  size_t stride = (size_t)gridDim.x * blockDim.x;
  for (; i < total; i += stride) {
    size_t g = i >> 13, k = i & 8191;
    wkp[i] = (g < 1552) ? f2bf(ldf(wk, g * 8193 + k, isbf)) : (u16)0;
  }
}

__global__ void k_prep_wr(const void* __restrict__ wr, const void* __restrict__ wk,
                          const void* __restrict__ bk, const void* __restrict__ br,
                          float* __restrict__ wrp, float* __restrict__ biasC,
                          float* __restrict__ wlC, const int* __restrict__ flagp) {
  int isbf = *flagp;
  int i0 = blockIdx.x * blockDim.x + threadIdx.x;
  int stride = gridDim.x * blockDim.x;
  for (int j = i0; j < 1552 * 384; j += stride) {
    int g = j / 384, k = j - g * 384;
    wrp[j] = ldf(wr, g * 385 + k, isbf);
  }
  for (int g = i0; g < 1552; g += stride) {
    biasC[g] = ldf(bk, g, isbf) + ldf(br, g, isbf);
    wlC[g] = ldf(wk, (size_t)g * 8193 + 8192, isbf) + ldf(wr, g * 385 + 384, isbf);
  }
}

__global__ void k_repack_wc(const void* __restrict__ wc, u16* __restrict__ wcp,
                            const int* __restrict__ flagp) {
  int isbf = *flagp;
  int i0 = blockIdx.x * blockDim.x + threadIdx.x;
  int stride = gridDim.x * blockDim.x;
  for (int j = i0; j < 384 * 3840; j += stride) {
    int o = j / 3840;
    int r = j - o * 3840;
    int k = r / 384;
    int h = r - k * 384;
    wcp[j] = f2bf(ldf(wc, (o * 384 + h) * 10 + k, isbf));  // [o][h][k]->[o][k][h]
  }
}

// canonical fp32: [vt 12800][Ws 24576][bs 64][Wrs 24576][brs 384][bc 384]
//                 [Wo 49152][bo 128]  (total 112064 floats)
__global__ void k_cvt_smalls(const void* vt, const void* Ws, const void* bs,
                             const void* Wrs, const void* brs, const void* bc,
                             const void* Wo, const void* bo,
                             float* __restrict__ dst, const int* __restrict__ flagp) {
  int isbf = *flagp;
  int i = blockIdx.x * blockDim.x + threadIdx.x;
  int stride = gridDim.x * blockDim.x;
  for (; i < 112064; i += stride) {
    float v;
    if (i < 12800) v = ldf(vt, i, isbf);
    else if (i < 37376) v = ldf(Ws, i - 12800, isbf);
    else if (i < 37440) v = ldf(bs, i - 37376, isbf);
    else if (i < 62016) v = ldf(Wrs, i - 37440, isbf);
    else if (i < 62400) v = ldf(brs, i - 62016, isbf);
    else if (i < 62784) v = ldf(bc, i - 62400, isbf);
    else if (i < 111936) v = ldf(Wo, i - 62784, isbf);
    else v = ldf(bo, i - 111936, isbf);
    dst[i] = v;
  }
}

// ------------------------- PH1: gathered GEMM -> XK (bf16), MFMA -----------
// grid (13 g-tiles, 100 m-tiles), 256 threads. Tile 128x128, BK=64 bf16.
__global__ __launch_bounds__(256) void k_gemm_xk(
    const int* __restrict__ node_ids, const u16* __restrict__ embB,
    const u16* __restrict__ wkp, const float* __restrict__ vtF,
    const float* __restrict__ biasC, const float* __restrict__ wlC,
    u16* __restrict__ xkb) {
  __shared__ alignas(16) u16 As[128 * 64];
  __shared__ alignas(16) u16 Bs[128 * 64];
  int tid = threadIdx.x;
  int m0 = blockIdx.y * 128;
  int g0 = blockIdx.x * 128;
  int lane = tid & 63, w = tid >> 6;
  int wy = w >> 1, wx = w & 1;
  f32x4 acc[4][4];
#pragma unroll
  for (int i = 0; i < 4; ++i)
#pragma unroll
    for (int j = 0; j < 4; ++j) acc[i][j] = (f32x4){0.f, 0.f, 0.f, 0.f};

  int r = tid >> 1, halfsel = tid & 1;
  int l15 = lane & 15, lq = lane >> 4;

  for (int kt = 0; kt < 128; ++kt) {
    __syncthreads();
    {
      int id = node_ids[(size_t)(m0 + r) * 64 + (kt >> 1)];
      const uint4* src =
          (const uint4*)(embB + (size_t)id * 128 + (kt & 1) * 64 + halfsel * 32);
      uint4* dst = (uint4*)(As + r * 64 + halfsel * 32);
      uint4 a0 = src[0], a1 = src[1], a2 = src[2], a3 = src[3];
      dst[0] = a0; dst[1] = a1; dst[2] = a2; dst[3] = a3;
    }
    {
      const uint4* src = (const uint4*)(wkp + (size_t)(g0 + r) * 8192 +
                                        (size_t)kt * 64 + halfsel * 32);
      uint4* dst = (uint4*)(Bs + r * 64 + halfsel * 32);
      uint4 b0 = src[0], b1 = src[1], b2 = src[2], b3 = src[3];
      dst[0] = b0; dst[1] = b1; dst[2] = b2; dst[3] = b3;
    }
    __syncthreads();
    const u16* Ab = As + (wy * 64 + l15) * 64 + lq * 8;
    const u16* Bb = Bs + (wx * 64 + l15) * 64 + lq * 8;
#pragma unroll
    for (int ks = 0; ks < 2; ++ks) {
      bf16x8 av[4], bv[4];
#pragma unroll
      for (int i = 0; i < 4; ++i) av[i] = *(const bf16x8*)(Ab + ks * 32 + i * 1024);
#pragma unroll
      for (int j = 0; j < 4; ++j) bv[j] = *(const bf16x8*)(Bb + ks * 32 + j * 1024);
#pragma unroll
      for (int i = 0; i < 4; ++i)
#pragma unroll
        for (int j = 0; j < 4; ++j)
          acc[i][j] =
              __builtin_amdgcn_mfma_f32_16x16x32_bf16(av[i], bv[j], acc[i][j], 0, 0, 0);
    }
  }
  float vt[4][4];
#pragma unroll
  for (int i = 0; i < 4; ++i)
#pragma unroll
    for (int p = 0; p < 4; ++p)
      vt[i][p] = vtF[m0 + wy * 64 + i * 16 + lq * 4 + p];
#pragma unroll
  for (int j = 0; j < 4; ++j) {
    int gcol = g0 + wx * 64 + j * 16 + l15;
    if (gcol < 1552) {
      float bC = biasC[gcol], wC = wlC[gcol];
#pragma unroll
      for (int i = 0; i < 4; ++i)
#pragma unroll
        for (int p = 0; p < 4; ++p) {
          int grow = m0 + wy * 64 + i * 16 + lq * 4 + p;
          xkb[(size_t)grow * 1552 + gcol] = f2bf(acc[i][j][p] + bC + vt[i][p] * wC);
        }
    }
  }
}

// ------------------------- monolithic scan + final (fp32 out) --------------
__global__ __launch_bounds__(256) void k_scan(
    const u16* __restrict__ xkb, const float* __restrict__ wrp,
    const float* __restrict__ smalls, const u16* __restrict__ wcp,
    const unsigned char* __restrict__ am, float* __restrict__ out) {
  const float* WsF = smalls + 12800;
  const float* bsF = smalls + 37376;
  const float* WrsF = smalls + 37440;
  const float* brsF = smalls + 62016;
  const float* bcF = smalls + 62400;
  const float* WoF = smalls + 62784;
  const float* boF = smalls + 111936;
  __shared__ alignas(16) float hS[384];
  __shared__ alignas(16) float cS[384];
  __shared__ alignas(16) float xo[1552];
  __shared__ alignas(16) float winH[10][384];
  __shared__ alignas(16) float winD[10];
  __shared__ alignas(16) float fm8[8], im8[8], ldS[10];
  __shared__ alignas(16) float ti[384], us[64], rnnS[384];
  __shared__ int npadS[50];
  __shared__ int lastSh;
  int tid = threadIdx.x;
  int b = blockIdx.x;

  if (tid < 50) {
    const unsigned char* mr = am + ((size_t)b * 50 + tid) * 64;
    int all1 = 1;
    for (int q = 0; q < 64; ++q) all1 &= (mr[q] != 0);
    npadS[tid] = all1 ? 0 : 1;
  }
  for (int i = tid; i < 384; i += 256) { hS[i] = 0.f; cS[i] = 0.f; }
  for (int i = tid; i < 3840; i += 256) ((float*)winH)[i] = 0.f;
  if (tid < 10) winD[tid] = 0.f;
  __syncthreads();
  if (tid == 0) {
    int c = 0;
    for (int v = 0; v < 50; ++v) c += npadS[v];
    int lv = c - 1;
    lastSh = lv < 0 ? 0 : lv;
  }
  __syncthreads();
  int T = lastSh;

  for (int t = 0; t <= T; ++t) {
    const u16* xkrow = xkb + ((size_t)b * 50 + t) * 1552;
    for (int g = tid; g < 1552; g += 256) {
      const float* wr = wrp + (size_t)g * 384;
      float s = 0.f;
#pragma unroll 4
      for (int k = 0; k < 384; k += 4) {
        f32x4 hv = *(const f32x4*)&hS[k];
        f32x4 wv = *(const f32x4*)(wr + k);
        s += hv[0] * wv[0] + hv[1] * wv[1] + hv[2] * wv[2] + hv[3] * wv[3];
      }
      xo[g] = bf2f(xkrow[g]) + s;
    }
    __syncthreads();
    if (tid == 0) {
      float z[8], e[8], m, s2, inv, run, fsum;
      m = -1e30f;
      for (int j = 0; j < 8; ++j) { z[j] = xo[j]; m = fmaxf(m, z[j]); }
      s2 = 0.f;
      for (int j = 0; j < 8; ++j) { e[j] = __expf(z[j] - m); s2 += e[j]; }
      inv = 1.f / s2; run = 0.f; fsum = 0.f;
      for (int j = 0; j < 8; ++j) { run += e[j] * inv; fm8[j] = run; fsum += run; }
      winD[t % 10] = 1.f - fsum * 0.125f;
      m = -1e30f;
      for (int j = 0; j < 8; ++j) { z[j] = xo[8 + j]; m = fmaxf(m, z[j]); }
      s2 = 0.f;
      for (int j = 0; j < 8; ++j) { e[j] = __expf(z[j] - m); s2 += e[j]; }
      inv = 1.f / s2; run = 0.f;
      for (int j = 7; j >= 0; --j) { run += e[j] * inv; im8[j] = run; }
    }
    __syncthreads();
    for (int h = tid; h < 384; h += 256) {
      int l = h / 48;
      float fg = sigf(xo[16 + h]);
      float ig = sigf(xo[16 + h + 384]);
      float og = sigf(xo[16 + h + 768]);
      float ci = tanhf_(xo[16 + h + 1152]);
      float cl = cS[h];
      float fm = fm8[l], im = im8[l];
      float ov = fm * im;
      float cn = ov * (fg * cl + ig * ci) + (fm - ov) * cl + (im - ov) * ci;
      float hn = og * tanhf_(cn);
      cS[h] = cn;
      hS[h] = hn;
      winH[t % 10][h] = hn;
    }
    __syncthreads();
  }

  if (tid == 0) {
    float cum = 0.f, cv[10];
    for (int k = 0; k < 10; ++k) {
      int s = T - 9 + k;
      float dk = (s >= 0) ? winD[s % 10] : 0.f;
      cum += dk;
      cv[k] = cum;
    }
    float m = cv[0];
    for (int k = 1; k < 10; ++k) m = fmaxf(m, cv[k]);
    float ssum = 0.f, ee[10];
    for (int k = 0; k < 10; ++k) { ee[k] = __expf(cv[k] - m); ssum += ee[k]; }
    float inv = 1.f / ssum;
    for (int k = 0; k < 10; ++k) ldS[k] = ee[k] * inv;
  }
  __syncthreads();
  for (int h = tid; h < 384; h += 256) {
    float ssum = 0.f;
    for (int k = 0; k < 10; ++k) {
      int s = T - 9 + k;
      float hv = (s >= 0) ? winH[s % 10][h] : 0.f;
      ssum += hv * ldS[k];
    }
    ti[h] = ssum * 0.1f;
  }
  __syncthreads();
  if (tid < 64) {
    float a = bsF[tid];
    const float* wr = WsF + (size_t)tid * 384;
    for (int h = 0; h < 384; ++h) a += wr[h] * ti[h];
    us[tid] = fmaxf(a, 0.f);
  }
  __syncthreads();
  for (int o = tid; o < 384; o += 256) {
    float th = brsF[o];
    const float* wr = WrsF + (size_t)o * 64;
    for (int k = 0; k < 64; ++k) th += wr[k] * us[k];
    th = sigf(th);
    float cacc = bcF[o];
    for (int k = 0; k < 10; ++k) {
      int s = T - 9 + k;
      if (s < 0) continue;
      const u16* wrow = wcp + ((size_t)o * 10 + k) * 384;
      const float* lrow = winH[s % 10];
      float d = 0.f;
      for (int h8 = 0; h8 < 48; ++h8) d += dot8_bf(wrow + h8 * 8, lrow + h8 * 8);
      cacc += d * ldS[k];
    }
    rnnS[o] = th * cacc + hS[o];
  }
  __syncthreads();
  if (tid < 128) {  // FP32 OUTPUT — the round-8 fix
    float a = boF[tid];
    const float* wr = WoF + (size_t)tid * 384;
    for (int h = 0; h < 384; ++h) a += wr[h] * rnnS[h];
    out[(size_t)b * 128 + tid] = a;
  }
}

// ------------------------- launch ------------------------------------------
extern "C" void kernel_launch(void* const* d_in, const int* in_sizes, int n_in,
                              void* d_out, int out_size, void* d_ws, size_t ws_size,
                              hipStream_t stream) {
  const int* node_ids = (const int*)d_in[0];
  const void* vtR = d_in[3];
  const unsigned char* am = (const unsigned char*)d_in[5];
  const void* embR = d_in[6];
  const void* WkR = d_in[7];
  const void* bkR = d_in[8];
  const void* WrR = d_in[9];
  const void* brR = d_in[10];
  const void* WsR = d_in[11];
  const void* bsR = d_in[12];
  const void* WrsR = d_in[13];
  const void* brsR = d_in[14];
  const void* WcR = d_in[15];
  const void* bcR = d_in[16];
  const void* WoR = d_in[17];
  const void* boR = d_in[18];
  (void)in_sizes; (void)n_in; (void)out_size; (void)ws_size;

  char* ws = (char*)d_ws;
  size_t off = 0;
  auto alloc = [&](size_t bytes) {
    void* p = ws + off;
    off = (off + bytes + 255) & ~(size_t)255;
    return p;
  };
  int* flagp = (int*)alloc(4);
  u16* embB = (u16*)alloc((size_t)10001 * 128 * 2);
  u16* WkP = (u16*)alloc((size_t)1664 * 8192 * 2);
  float* WrP = (float*)alloc((size_t)1552 * 384 * 4);
  float* biasC = (float*)alloc(1552 * 4);
  float* wlC = (float*)alloc(1552 * 4);
  float* smalls = (float*)alloc((size_t)112064 * 4);
  u16* XKb = (u16*)alloc((size_t)12800 * 1552 * 2);
  u16* WcP = (u16*)alloc((size_t)384 * 3840 * 2);

  k_detect<<<dim3(1), dim3(64), 0, stream>>>((const unsigned int*)embR, flagp);
  k_cvt_emb<<<dim3(1024), dim3(256), 0, stream>>>(embR, embB, flagp);
  k_repack_wk<<<dim3(2048), dim3(256), 0, stream>>>(WkR, WkP, flagp);
  k_prep_wr<<<dim3(512), dim3(256), 0, stream>>>(WrR, WkR, bkR, brR, WrP, biasC,
                                                 wlC, flagp);
  k_repack_wc<<<dim3(512), dim3(256), 0, stream>>>(WcR, WcP, flagp);
  k_cvt_smalls<<<dim3(128), dim3(256), 0, stream>>>(vtR, WsR, bsR, WrsR, brsR,
                                                    bcR, WoR, boR, smalls, flagp);

  k_gemm_xk<<<dim3(13, 100), dim3(256), 0, stream>>>(node_ids, embB, WkP, smalls,
                                                     biasC, wlC, XKb);

  k_scan<<<dim3(256), dim3(256), 0, stream>>>(XKb, WrP, smalls, WcP, am,
                                              (float*)d_out);
}